// Round 1
// baseline (503.637 us; speedup 1.0000x reference)
//
#include <hip/hip_runtime.h>
#include <math.h>

#define BB 4
#define CIN 256
#define GC 64
#define PL 64
#define HL 128
#define WL 128
#define HH 256
#define WW 256
#define CTOT (CIN + GC)          /* 320 */
#define NPIX (BB * HH * WW)      /* 262144 */
#define HW (HH * WW)             /* 65536 */

/* ws layout (bytes) */
#define XV_OFF    0               /* 4*64*256*256 floats = 67108864 B */
#define STATS_OFF 67108864        /* 128 floats */
#define WT_OFF    67109376        /* 320*64 floats = 81920 B */

__global__ void k_transpose_w(const float* __restrict__ W, float* __restrict__ Wt) {
    int i = blockIdx.x * blockDim.x + threadIdx.x;
    if (i >= CTOT * PL) return;
    int c = i >> 6, o = i & 63;
    Wt[i] = W[o * CTOT + c];
}

__global__ __launch_bounds__(256) void k_conv(const float* __restrict__ x,
                                              const float* __restrict__ guide,
                                              const float* __restrict__ Wt,
                                              float* __restrict__ xv) {
    int bh = blockIdx.x;          /* b*HH + h */
    int b = bh >> 8;
    int h = bh & 255;
    int w = threadIdx.x;

    /* bilinear 2x upsample, half-pixel convention: coord = 0.5*i - 0.25 */
    int iy0, iy1; float wy0;
    { int m = h >> 1;
      if (h & 1) { iy0 = m; iy1 = (m + 1 < HL) ? m + 1 : HL - 1; wy0 = 0.75f; }
      else       { iy0 = (m - 1 >= 0) ? m - 1 : 0; iy1 = m;      wy0 = 0.25f; } }
    float wy1 = 1.0f - wy0;
    int ix0, ix1; float wx0;
    { int m = w >> 1;
      if (w & 1) { ix0 = m; ix1 = (m + 1 < WL) ? m + 1 : WL - 1; wx0 = 0.75f; }
      else       { ix0 = (m - 1 >= 0) ? m - 1 : 0; ix1 = m;      wx0 = 0.25f; } }
    float wx1 = 1.0f - wx0;

    float acc[PL];
#pragma unroll
    for (int o = 0; o < PL; ++o) acc[o] = 0.f;

    const float* xb = x + (size_t)b * CIN * (HL * WL);
    int o00 = iy0 * WL + ix0, o01 = iy0 * WL + ix1;
    int o10 = iy1 * WL + ix0, o11 = iy1 * WL + ix1;

    for (int c = 0; c < CIN; ++c) {
        const float* xc = xb + c * (HL * WL);
        float val = wy0 * (wx0 * xc[o00] + wx1 * xc[o01])
                  + wy1 * (wx0 * xc[o10] + wx1 * xc[o11]);
        const float* wr = Wt + c * PL;   /* wave-uniform address -> s_load */
#pragma unroll
        for (int o = 0; o < PL; ++o) acc[o] = fmaf(val, wr[o], acc[o]);
    }
    const float* gb = guide + (size_t)b * GC * HW + h * WW + w;
    for (int c = 0; c < GC; ++c) {
        float val = gb[(size_t)c * HW];
        const float* wr = Wt + (CIN + c) * PL;
#pragma unroll
        for (int o = 0; o < PL; ++o) acc[o] = fmaf(val, wr[o], acc[o]);
    }
    float* ob = xv + (size_t)b * PL * HW + h * WW + w;
#pragma unroll
    for (int o = 0; o < PL; ++o) ob[(size_t)o * HW] = acc[o];
}

__global__ __launch_bounds__(256) void k_attn(const float* __restrict__ guide,
                                              const float* __restrict__ xv,
                                              float* __restrict__ out) {
    int bh = blockIdx.x;
    int b = bh >> 8;
    int h = bh & 255;
    int w = threadIdx.x;

    int  voff[9];
    bool valid[9];
#pragma unroll
    for (int i = 0; i < 3; ++i)
#pragma unroll
        for (int j = 0; j < 3; ++j) {
            int hh = h + i - 1, ww = w + j - 1;
            bool ok = (hh >= 0) && (hh < HH) && (ww >= 0) && (ww < WW);
            valid[i * 3 + j] = ok;
            voff[i * 3 + j] = ok ? ((i - 1) * WW + (j - 1)) : 0;
        }

    float s[9];
#pragma unroll
    for (int k = 0; k < 9; ++k) s[k] = 0.f;

    const float* gq = guide + (size_t)b * GC * HW + h * WW + w;
    for (int c = 0; c < GC; ++c) {
        const float* gc = gq + (size_t)c * HW;
        float qv = gc[0];
#pragma unroll
        for (int k = 0; k < 9; ++k) s[k] = fmaf(qv, gc[voff[k]], s[k]);
    }

    /* scale; zero invalid BEFORE softmax (they participate with score 0) */
#pragma unroll
    for (int k = 0; k < 9; ++k) s[k] = valid[k] ? s[k] * 0.125f : 0.f;
    float m = s[0];
#pragma unroll
    for (int k = 1; k < 9; ++k) m = fmaxf(m, s[k]);
    float a[9];
    float denom = 0.f;
#pragma unroll
    for (int k = 0; k < 9; ++k) { a[k] = __expf(s[k] - m); denom += a[k]; }
    float inv = 1.f / denom;
    /* invalid neighbors have v == 0 -> drop them from the weighted sum */
#pragma unroll
    for (int k = 0; k < 9; ++k) a[k] = valid[k] ? a[k] * inv : 0.f;

    const float* vb = xv + (size_t)b * PL * HW + h * WW + w;
    float* ob = out + (size_t)b * PL * HW + h * WW + w;
    for (int c = 0; c < PL; ++c) {
        const float* vc = vb + (size_t)c * HW;
        float o = 0.f;
#pragma unroll
        for (int k = 0; k < 9; ++k) o = fmaf(a[k], vc[voff[k]], o);
        ob[(size_t)c * HW] = o;
    }
}

__global__ __launch_bounds__(256) void k_stats(const float* __restrict__ out,
                                               float* __restrict__ stats) {
    int bc = blockIdx.x >> 2;            /* b*PL + c */
    int c = bc & (PL - 1);
    const float4* p = (const float4*)(out + (size_t)bc * HW)
                      + (blockIdx.x & 3) * 4096 + threadIdx.x;
    float s = 0.f, q = 0.f;
#pragma unroll
    for (int i = 0; i < 16; ++i) {
        float4 v = p[i * 256];
        s += v.x + v.y + v.z + v.w;
        q += v.x * v.x + v.y * v.y + v.z * v.z + v.w * v.w;
    }
#pragma unroll
    for (int d = 32; d >= 1; d >>= 1) { s += __shfl_xor(s, d); q += __shfl_xor(q, d); }
    __shared__ float ls[4], lq[4];
    int wave = threadIdx.x >> 6;
    if ((threadIdx.x & 63) == 0) { ls[wave] = s; lq[wave] = q; }
    __syncthreads();
    if (threadIdx.x == 0) {
        atomicAdd(&stats[c],      ls[0] + ls[1] + ls[2] + ls[3]);
        atomicAdd(&stats[PL + c], lq[0] + lq[1] + lq[2] + lq[3]);
    }
}

__global__ __launch_bounds__(256) void k_norm(float* __restrict__ out,
                                              const float* __restrict__ stats,
                                              const float* __restrict__ gamma,
                                              const float* __restrict__ beta) {
    size_t idx = (size_t)blockIdx.x * 256 + threadIdx.x;   /* float4 index */
    int c = (int)((idx >> 14) & (PL - 1));
    float4 v = ((const float4*)out)[idx];
    float n = (float)NPIX;
    float mean = stats[c] / n;
    float var = stats[PL + c] / n - mean * mean;
    float sc = gamma[c] * rsqrtf(var + 1e-5f);
    float bs = beta[c] - mean * sc;
    v.x = fmaf(v.x, sc, bs);
    v.y = fmaf(v.y, sc, bs);
    v.z = fmaf(v.z, sc, bs);
    v.w = fmaf(v.w, sc, bs);
    ((float4*)out)[idx] = v;
}

extern "C" void kernel_launch(void* const* d_in, const int* in_sizes, int n_in,
                              void* d_out, int out_size, void* d_ws, size_t ws_size,
                              hipStream_t stream) {
    const float* x     = (const float*)d_in[0];
    const float* guide = (const float*)d_in[1];
    const float* Wc    = (const float*)d_in[2];
    const float* gamma = (const float*)d_in[3];
    const float* beta  = (const float*)d_in[4];
    float* out = (float*)d_out;

    char* ws = (char*)d_ws;
    float* xv    = (float*)(ws + XV_OFF);
    float* stats = (float*)(ws + STATS_OFF);
    float* Wt    = (float*)(ws + WT_OFF);

    hipMemsetAsync(stats, 0, 2 * PL * sizeof(float), stream);
    k_transpose_w<<<(CTOT * PL + 255) / 256, 256, 0, stream>>>(Wc, Wt);
    k_conv<<<BB * HH, 256, 0, stream>>>(x, guide, Wt, xv);
    k_attn<<<BB * HH, 256, 0, stream>>>(guide, xv, out);
    k_stats<<<BB * PL * 4, 256, 0, stream>>>(out, stats);
    k_norm<<<(NPIX * PL) / (256 * 4), 256, 0, stream>>>(out, stats, gamma, beta);
}

// Round 2
// 466.083 us; speedup vs baseline: 1.0806x; 1.0806x over previous
//
#include <hip/hip_runtime.h>
#include <math.h>

#define BB 4
#define CIN 256
#define GC 64
#define PL 64
#define HL 128
#define WL 128
#define HH 256
#define WW 256
#define CTOT (CIN + GC)          /* 320 */
#define NPIX (BB * HH * WW)      /* 262144 */
#define HW (HH * WW)             /* 65536 */

/* ws layout (bytes) */
#define XV_OFF    0               /* 4*64*256*256 floats = 67108864 B */
#define STATS_OFF 67108864        /* 128 floats */
#define WT_OFF    67109376        /* 320*64 floats = 81920 B */

__global__ void k_transpose_w(const float* __restrict__ W, float* __restrict__ Wt) {
    int i = blockIdx.x * blockDim.x + threadIdx.x;
    if (i >= CTOT * PL) return;
    int c = i >> 6, o = i & 63;
    Wt[i] = W[o * CTOT + c];
}

/* GEMM-structured 1x1 conv over (bilinear-upsampled x || guide).
 * Block: 256 threads = 4 waves. Block covers 64 consecutive pixels of row h.
 * Wave og owns output channels [og*16, og*16+16): acc[16] in registers.
 * Activations staged 8 channels/chunk in LDS; weights via uniform ptr -> s_load. */
__global__ __launch_bounds__(256) void k_conv(const float* __restrict__ x,
                                              const float* __restrict__ guide,
                                              const float* __restrict__ Wt,
                                              float* __restrict__ xv) {
    int blk = blockIdx.x;          /* [0, 4096) */
    int qw = blk & 3;
    int bh = blk >> 2;
    int h = bh & 255;
    int b = bh >> 8;
    int tid = threadIdx.x;
    int p = tid & 63;
    int og = tid >> 6;
    int og_u = __builtin_amdgcn_readfirstlane(og);   /* wave-uniform -> SGPR */
    int w = qw * 64 + p;

    /* bilinear 2x upsample, half-pixel convention */
    int iy0, iy1; float wy0;
    { int m = h >> 1;
      if (h & 1) { iy0 = m; iy1 = (m + 1 < HL) ? m + 1 : HL - 1; wy0 = 0.75f; }
      else       { iy0 = (m - 1 >= 0) ? m - 1 : 0; iy1 = m;      wy0 = 0.25f; } }
    float wy1 = 1.0f - wy0;
    int ix0, ix1; float wx0;
    { int m = w >> 1;
      if (w & 1) { ix0 = m; ix1 = (m + 1 < WL) ? m + 1 : WL - 1; wx0 = 0.75f; }
      else       { ix0 = (m - 1 >= 0) ? m - 1 : 0; ix1 = m;      wx0 = 0.25f; } }
    float wx1 = 1.0f - wx0;
    int o00 = iy0 * WL + ix0, o01 = iy0 * WL + ix1;
    int o10 = iy1 * WL + ix0, o11 = iy1 * WL + ix1;

    __shared__ float lact[8][64];
    float acc[16];
#pragma unroll
    for (int j = 0; j < 16; ++j) acc[j] = 0.f;

    const float* xb = x + (size_t)b * CIN * (HL * WL);
    const float* gb = guide + (size_t)b * GC * HW + h * WW + w;

    for (int c0 = 0; c0 < CTOT; c0 += 8) {
        /* stage: wave og stages channels c0+og*2, c0+og*2+1 */
#pragma unroll
        for (int e = 0; e < 2; ++e) {
            int c = c0 + og * 2 + e;
            float v;
            if (c < CIN) {
                const float* xc = xb + (size_t)c * (HL * WL);
                v = wy0 * (wx0 * xc[o00] + wx1 * xc[o01])
                  + wy1 * (wx0 * xc[o10] + wx1 * xc[o11]);
            } else {
                v = gb[(size_t)(c - CIN) * HW];
            }
            lact[og * 2 + e][p] = v;
        }
        __syncthreads();
        const float* wb = Wt + (size_t)c0 * PL + og_u * 16;   /* uniform -> s_load */
#pragma unroll
        for (int cc = 0; cc < 8; ++cc) {
            float a0 = lact[cc][p];
#pragma unroll
            for (int j = 0; j < 16; ++j) acc[j] = fmaf(a0, wb[cc * PL + j], acc[j]);
        }
        __syncthreads();
    }

    float* ob = xv + ((size_t)b * PL + og * 16) * HW + h * WW + w;
#pragma unroll
    for (int j = 0; j < 16; ++j) ob[(size_t)j * HW] = acc[j];
}

/* Local 3x3 attention, 4 pixels per thread (float4).
 * OOB neighbors contribute score 0 (still inside the 9-way softmax) and v=0 —
 * reproduced exactly by feeding zero values for OOB loads, no masks needed. */
__global__ __launch_bounds__(256) void k_attn(const float* __restrict__ guide,
                                              const float* __restrict__ xv,
                                              float* __restrict__ out) {
    int blk = blockIdx.x;            /* [0, 256) */
    int b = blk >> 6;
    int rg = blk & 63;
    int tid = threadIdx.x;
    int r_sub = tid >> 6;
    int p = tid & 63;
    int h = rg * 4 + r_sub;
    int col = 4 * p;

    bool rok[3];
    rok[0] = (h - 1) >= 0;
    rok[1] = true;
    rok[2] = (h + 1) < HH;
    bool lok = p > 0;
    bool r_ok = p < 63;

    float s[4][9];
#pragma unroll
    for (int xq = 0; xq < 4; ++xq)
#pragma unroll
        for (int k = 0; k < 9; ++k) s[xq][k] = 0.f;

    const float* gbase = guide + (size_t)b * GC * HW + h * WW + col;

    for (int c = 0; c < GC; ++c) {
        const float* gp = gbase + (size_t)c * HW;
        float arr[3][6];
#pragma unroll
        for (int r = 0; r < 3; ++r) {
            int ro = (r - 1) * WW;
            float4 m = rok[r] ? *(const float4*)(gp + ro)
                              : make_float4(0.f, 0.f, 0.f, 0.f);
            arr[r][0] = (rok[r] && lok)  ? gp[ro - 1] : 0.f;
            arr[r][1] = m.x; arr[r][2] = m.y; arr[r][3] = m.z; arr[r][4] = m.w;
            arr[r][5] = (rok[r] && r_ok) ? gp[ro + 4] : 0.f;
        }
        float q[4] = { arr[1][1], arr[1][2], arr[1][3], arr[1][4] };
#pragma unroll
        for (int xq = 0; xq < 4; ++xq)
#pragma unroll
            for (int r = 0; r < 3; ++r)
#pragma unroll
                for (int dj = 0; dj < 3; ++dj)
                    s[xq][r * 3 + dj] = fmaf(q[xq], arr[r][xq + dj], s[xq][r * 3 + dj]);
    }

    /* softmax over 9 (zeros for OOB already correct) */
#pragma unroll
    for (int xq = 0; xq < 4; ++xq) {
        float mx = s[xq][0] * 0.125f;
#pragma unroll
        for (int k = 0; k < 9; ++k) { s[xq][k] *= 0.125f; mx = fmaxf(mx, s[xq][k]); }
        float denom = 0.f;
#pragma unroll
        for (int k = 0; k < 9; ++k) { s[xq][k] = __expf(s[xq][k] - mx); denom += s[xq][k]; }
        float inv = 1.f / denom;
#pragma unroll
        for (int k = 0; k < 9; ++k) s[xq][k] *= inv;
    }

    const float* vbase = xv + (size_t)b * PL * HW + h * WW + col;
    float* obase = out + (size_t)b * PL * HW + h * WW + col;

    for (int c = 0; c < PL; ++c) {
        const float* vp = vbase + (size_t)c * HW;
        float arr[3][6];
#pragma unroll
        for (int r = 0; r < 3; ++r) {
            int ro = (r - 1) * WW;
            float4 m = rok[r] ? *(const float4*)(vp + ro)
                              : make_float4(0.f, 0.f, 0.f, 0.f);
            arr[r][0] = (rok[r] && lok)  ? vp[ro - 1] : 0.f;
            arr[r][1] = m.x; arr[r][2] = m.y; arr[r][3] = m.z; arr[r][4] = m.w;
            arr[r][5] = (rok[r] && r_ok) ? vp[ro + 4] : 0.f;
        }
        float4 o = make_float4(0.f, 0.f, 0.f, 0.f);
#pragma unroll
        for (int r = 0; r < 3; ++r)
#pragma unroll
            for (int dj = 0; dj < 3; ++dj) {
                int k = r * 3 + dj;
                o.x = fmaf(s[0][k], arr[r][0 + dj], o.x);
                o.y = fmaf(s[1][k], arr[r][1 + dj], o.y);
                o.z = fmaf(s[2][k], arr[r][2 + dj], o.z);
                o.w = fmaf(s[3][k], arr[r][3 + dj], o.w);
            }
        *(float4*)(obase + (size_t)c * HW) = o;
    }
}

__global__ __launch_bounds__(256) void k_stats(const float* __restrict__ out,
                                               float* __restrict__ stats) {
    int bc = blockIdx.x >> 2;            /* b*PL + c */
    int c = bc & (PL - 1);
    const float4* p = (const float4*)(out + (size_t)bc * HW)
                      + (blockIdx.x & 3) * 4096 + threadIdx.x;
    float s = 0.f, q = 0.f;
#pragma unroll
    for (int i = 0; i < 16; ++i) {
        float4 v = p[i * 256];
        s += v.x + v.y + v.z + v.w;
        q += v.x * v.x + v.y * v.y + v.z * v.z + v.w * v.w;
    }
#pragma unroll
    for (int d = 32; d >= 1; d >>= 1) { s += __shfl_xor(s, d); q += __shfl_xor(q, d); }
    __shared__ float ls[4], lq[4];
    int wave = threadIdx.x >> 6;
    if ((threadIdx.x & 63) == 0) { ls[wave] = s; lq[wave] = q; }
    __syncthreads();
    if (threadIdx.x == 0) {
        atomicAdd(&stats[c],      ls[0] + ls[1] + ls[2] + ls[3]);
        atomicAdd(&stats[PL + c], lq[0] + lq[1] + lq[2] + lq[3]);
    }
}

__global__ __launch_bounds__(256) void k_norm(float* __restrict__ out,
                                              const float* __restrict__ stats,
                                              const float* __restrict__ gamma,
                                              const float* __restrict__ beta) {
    size_t idx = (size_t)blockIdx.x * 256 + threadIdx.x;   /* float4 index */
    int c = (int)((idx >> 14) & (PL - 1));
    float4 v = ((const float4*)out)[idx];
    float n = (float)NPIX;
    float mean = stats[c] / n;
    float var = stats[PL + c] / n - mean * mean;
    float sc = gamma[c] * rsqrtf(var + 1e-5f);
    float bs = beta[c] - mean * sc;
    v.x = fmaf(v.x, sc, bs);
    v.y = fmaf(v.y, sc, bs);
    v.z = fmaf(v.z, sc, bs);
    v.w = fmaf(v.w, sc, bs);
    ((float4*)out)[idx] = v;
}

extern "C" void kernel_launch(void* const* d_in, const int* in_sizes, int n_in,
                              void* d_out, int out_size, void* d_ws, size_t ws_size,
                              hipStream_t stream) {
    const float* x     = (const float*)d_in[0];
    const float* guide = (const float*)d_in[1];
    const float* Wc    = (const float*)d_in[2];
    const float* gamma = (const float*)d_in[3];
    const float* beta  = (const float*)d_in[4];
    float* out = (float*)d_out;

    char* ws = (char*)d_ws;
    float* xv    = (float*)(ws + XV_OFF);
    float* stats = (float*)(ws + STATS_OFF);
    float* Wt    = (float*)(ws + WT_OFF);

    hipMemsetAsync(stats, 0, 2 * PL * sizeof(float), stream);
    k_transpose_w<<<(CTOT * PL + 255) / 256, 256, 0, stream>>>(Wc, Wt);
    k_conv<<<BB * HH * 4, 256, 0, stream>>>(x, guide, Wt, xv);
    k_attn<<<256, 256, 0, stream>>>(guide, xv, out);
    k_stats<<<BB * PL * 4, 256, 0, stream>>>(out, stats);
    k_norm<<<(NPIX * PL) / (256 * 4), 256, 0, stream>>>(out, stats, gamma, beta);
}

// Round 5
// 318.015 us; speedup vs baseline: 1.5837x; 1.4656x over previous
//
#include <hip/hip_runtime.h>
#include <math.h>

#define BB 4
#define CIN 256
#define GC 64
#define PL 64
#define HL 128
#define WL 128
#define HH 256
#define WW 256
#define HWLO (HL*WL)             /* 16384 */
#define HW (HH*WW)               /* 65536 */
#define NPIX (BB*HW)

typedef __attribute__((ext_vector_type(8))) short bf16x8;
typedef __attribute__((ext_vector_type(4))) float f32x4;

/* ws layout */
#define XV_OFF 0u                 /* bf16 xv: 4*64*65536*2 = 33554432 B */
#define Y1_OFF 33554432u          /* fp32 y1: 4*64*16384*4 = 16777216 B */
#define STATS_OFF 50331648u       /* 128 floats */

static __device__ __forceinline__ unsigned short f2bf(float f) {
    unsigned int u = __float_as_uint(f);
    u = (u + 0x7FFFu + ((u >> 16) & 1u)) >> 16;   /* RNE */
    return (unsigned short)u;
}
static __device__ __forceinline__ float bf2f(unsigned short s) {
    return __uint_as_float(((unsigned int)s) << 16);
}

/* y1[b][64][128*128] = W_x(64x256) * x  — bf16 MFMA GEMM, low-res.
 * Block: 512 thr = 8 waves, one low-res row (128 px). Wave owns 16 px. */
__global__ __launch_bounds__(512) void k_gemm_lo(const float* __restrict__ x,
                                                 const float* __restrict__ Wc,
                                                 float* __restrict__ y1) {
    __shared__ unsigned short lw[64 * 264];   /* W bf16 [64][256+8] */
    __shared__ unsigned short la[128 * 40];   /* act bf16 [128 px][32+8 k] */
    int t = threadIdx.x;
    int b = blockIdx.x >> 7;
    int row = blockIdx.x & 127;
    int lane = t & 63, wid = t >> 6;
    int g = lane >> 4, fr = lane & 15;

    for (int i = t; i < 64 * 256; i += 512) {
        int m = i >> 8, k = i & 255;
        lw[m * 264 + k] = f2bf(Wc[m * 320 + k]);
    }

    f32x4 acc[4];
#pragma unroll
    for (int m = 0; m < 4; ++m) acc[m] = (f32x4){0.f, 0.f, 0.f, 0.f};

    const float* xb = x + (size_t)b * CIN * HWLO + row * WL;
    int px = t & 127, kg = t >> 7;            /* staging: (px, 8-k group) */

    for (int kt = 0; kt < 8; ++kt) {
        int k0 = kt * 32;
        short pk[8];
#pragma unroll
        for (int j = 0; j < 8; ++j)
            pk[j] = (short)f2bf(xb[(size_t)(k0 + kg * 8 + j) * HWLO + px]);
        __syncthreads();                       /* prev compute done with la */
        *(bf16x8*)(&la[px * 40 + kg * 8]) = *(bf16x8*)pk;
        __syncthreads();
        bf16x8 bfr = *(const bf16x8*)(&la[(wid * 16 + fr) * 40 + g * 8]);
#pragma unroll
        for (int m = 0; m < 4; ++m) {
            bf16x8 af = *(const bf16x8*)(&lw[(m * 16 + fr) * 264 + k0 + g * 8]);
            acc[m] = __builtin_amdgcn_mfma_f32_16x16x32_bf16(af, bfr, acc[m], 0, 0, 0);
        }
    }

    float* yb = y1 + (size_t)b * 64 * HWLO + row * WL + wid * 16 + fr;
#pragma unroll
    for (int m = 0; m < 4; ++m)
#pragma unroll
        for (int r = 0; r < 4; ++r)
            yb[(size_t)(m * 16 + g * 4 + r) * HWLO] = acc[m][r];
}

/* xv[b][64][256*256] (bf16) = upsample(y1) + W_g(64x64) * guide.
 * Block: 512 thr = 8 waves, one hi-res row (256 px). Wave owns 32 px. */
__global__ __launch_bounds__(512) void k_conv_hi(const float* __restrict__ guide,
                                                 const float* __restrict__ Wc,
                                                 const float* __restrict__ y1,
                                                 unsigned short* __restrict__ xv) {
    __shared__ unsigned short lg[256 * 72];   /* guide bf16 [256 px][64+8 k]; aliased later */
    __shared__ unsigned short lw[64 * 72];    /* W_g bf16 [64][64+8] */
    int t = threadIdx.x;
    int bid = blockIdx.x;
    int swz = (bid & 7) * 128 + (bid >> 3);   /* XCD-chunked, bijective (nwg=1024) */
    int b = swz >> 8, h = swz & 255;
    int lane = t & 63, wid = t >> 6, g = lane >> 4, fr = lane & 15;

    for (int i = t; i < 64 * 64; i += 512) {
        int m = i >> 6, k = i & 63;
        lw[m * 72 + k] = f2bf(Wc[m * 320 + 256 + k]);
    }
    const float* gb = guide + (size_t)b * GC * HW + (size_t)h * WW;
#pragma unroll
    for (int q = 0; q < 4; ++q) {
        int a = t + q * 512;
        int px = a & 255, kg = a >> 8;
        short pk[8];
#pragma unroll
        for (int j = 0; j < 8; ++j)
            pk[j] = (short)f2bf(gb[(size_t)(kg * 8 + j) * HW + px]);
        *(bf16x8*)(&lg[px * 72 + kg * 8]) = *(bf16x8*)pk;
    }
    __syncthreads();

    f32x4 acc[4][2];
#pragma unroll
    for (int m = 0; m < 4; ++m)
#pragma unroll
        for (int n = 0; n < 2; ++n) acc[m][n] = (f32x4){0.f, 0.f, 0.f, 0.f};

#pragma unroll
    for (int kt = 0; kt < 2; ++kt) {
        bf16x8 bfr[2];
#pragma unroll
        for (int n = 0; n < 2; ++n)
            bfr[n] = *(const bf16x8*)(&lg[(wid * 32 + n * 16 + fr) * 72 + kt * 32 + g * 8]);
#pragma unroll
        for (int m = 0; m < 4; ++m) {
            bf16x8 af = *(const bf16x8*)(&lw[(m * 16 + fr) * 72 + kt * 32 + g * 8]);
#pragma unroll
            for (int n = 0; n < 2; ++n)
                acc[m][n] = __builtin_amdgcn_mfma_f32_16x16x32_bf16(af, bfr[n], acc[m][n], 0, 0, 0);
        }
    }
    __syncthreads();                           /* lg (guide view) dead */

    /* stage wy-blended y1 row: [64 ch][128+4 pad] fp32, aliases lg */
    float* yb = (float*)lg;
    int m0 = h >> 1; int iy0, iy1; float wy0;
    if (h & 1) { iy0 = m0; iy1 = (m0 + 1 < HL) ? m0 + 1 : HL - 1; wy0 = 0.75f; }
    else       { iy0 = (m0 - 1 >= 0) ? m0 - 1 : 0; iy1 = m0;      wy0 = 0.25f; }
    float wy1 = 1.f - wy0;
    const float* y1b = y1 + (size_t)b * 64 * HWLO;
    for (int i = t; i < 64 * 128; i += 512) {
        int ch = i >> 7, ix = i & 127;
        yb[ch * 132 + ix] = wy0 * y1b[(size_t)ch * HWLO + iy0 * WL + ix]
                          + wy1 * y1b[(size_t)ch * HWLO + iy1 * WL + ix];
    }
    __syncthreads();

    int ix0v[2], ix1v[2]; float wx0v[2];
#pragma unroll
    for (int n = 0; n < 2; ++n) {
        int w = wid * 32 + n * 16 + fr;
        int mm = w >> 1;
        if (w & 1) { ix0v[n] = mm; ix1v[n] = (mm + 1 < WL) ? mm + 1 : WL - 1; wx0v[n] = 0.75f; }
        else       { ix0v[n] = (mm - 1 >= 0) ? mm - 1 : 0; ix1v[n] = mm;      wx0v[n] = 0.25f; }
    }
    unsigned short* xb = xv + (size_t)b * 64 * HW + (size_t)h * WW;
#pragma unroll
    for (int m = 0; m < 4; ++m)
#pragma unroll
        for (int n = 0; n < 2; ++n) {
            int w = wid * 32 + n * 16 + fr;
#pragma unroll
            for (int r = 0; r < 4; ++r) {
                int ch = m * 16 + g * 4 + r;
                float up = wx0v[n] * yb[ch * 132 + ix0v[n]]
                         + (1.f - wx0v[n]) * yb[ch * 132 + ix1v[n]];
                xb[(size_t)ch * HW + w] = f2bf(acc[m][n][r] + up);
            }
        }
}

/* local 3x3 attention: block = one row h; thread = one pixel w.
 * LDS-staged 8-channel x 3-row strips; zero halos reproduce zero-pad softmax. */
__global__ __launch_bounds__(256) void k_attn(const float* __restrict__ guide,
                                              const unsigned short* __restrict__ xv,
                                              float* __restrict__ out) {
    __shared__ float ls[8][3][264];
    int t = threadIdx.x;
    int bid = blockIdx.x;
    int swz = (bid & 7) * 128 + (bid >> 3);
    int b = swz >> 8, h = swz & 255;
    bool rok[3] = { h > 0, true, h < HH - 1 };
    int hr[3] = { h > 0 ? h - 1 : 0, h, h < HH - 1 ? h + 1 : HH - 1 };

    float s[9];
#pragma unroll
    for (int k = 0; k < 9; ++k) s[k] = 0.f;

    const float* gB = guide + (size_t)b * GC * HW;
    for (int c0 = 0; c0 < GC; c0 += 8) {
#pragma unroll
        for (int cc = 0; cc < 8; ++cc)
#pragma unroll
            for (int r = 0; r < 3; ++r)
                ls[cc][r][1 + t] = rok[r] ? gB[(size_t)(c0 + cc) * HW + (size_t)hr[r] * WW + t] : 0.f;
        if (t < 24) { int cc = t / 3, r = t % 3; ls[cc][r][0] = 0.f; ls[cc][r][257] = 0.f; }
        __syncthreads();
#pragma unroll
        for (int cc = 0; cc < 8; ++cc) {
            float q = ls[cc][1][1 + t];
#pragma unroll
            for (int r = 0; r < 3; ++r)
#pragma unroll
                for (int dj = 0; dj < 3; ++dj)
                    s[r * 3 + dj] = fmaf(q, ls[cc][r][t + dj], s[r * 3 + dj]);
        }
        __syncthreads();
    }

    float mx = s[0] * 0.125f;
#pragma unroll
    for (int k = 0; k < 9; ++k) { s[k] *= 0.125f; mx = fmaxf(mx, s[k]); }
    float den = 0.f;
#pragma unroll
    for (int k = 0; k < 9; ++k) { s[k] = __expf(s[k] - mx); den += s[k]; }
    float inv = 1.f / den;
#pragma unroll
    for (int k = 0; k < 9; ++k) s[k] *= inv;

    const unsigned short* vB = xv + (size_t)b * 64 * HW;
    float* oB = out + (size_t)b * 64 * HW + (size_t)h * WW + t;
    for (int c0 = 0; c0 < PL; c0 += 8) {
#pragma unroll
        for (int cc = 0; cc < 8; ++cc)
#pragma unroll
            for (int r = 0; r < 3; ++r)
                ls[cc][r][1 + t] = rok[r] ? bf2f(vB[(size_t)(c0 + cc) * HW + (size_t)hr[r] * WW + t]) : 0.f;
        if (t < 24) { int cc = t / 3, r = t % 3; ls[cc][r][0] = 0.f; ls[cc][r][257] = 0.f; }
        __syncthreads();
#pragma unroll
        for (int cc = 0; cc < 8; ++cc) {
            float o = 0.f;
#pragma unroll
            for (int r = 0; r < 3; ++r)
#pragma unroll
                for (int dj = 0; dj < 3; ++dj)
                    o = fmaf(s[r * 3 + dj], ls[cc][r][t + dj], o);
            oB[(size_t)(c0 + cc) * HW] = o;
        }
        __syncthreads();
    }
}

__global__ __launch_bounds__(256) void k_stats(const float* __restrict__ out,
                                               float* __restrict__ stats) {
    int bc = blockIdx.x >> 2;
    int c = bc & (PL - 1);
    const float4* p = (const float4*)(out + (size_t)bc * HW)
                      + (blockIdx.x & 3) * 4096 + threadIdx.x;
    float s = 0.f, q = 0.f;
#pragma unroll
    for (int i = 0; i < 16; ++i) {
        float4 v = p[i * 256];
        s += v.x + v.y + v.z + v.w;
        q += v.x * v.x + v.y * v.y + v.z * v.z + v.w * v.w;
    }
#pragma unroll
    for (int d = 32; d >= 1; d >>= 1) { s += __shfl_xor(s, d); q += __shfl_xor(q, d); }
    __shared__ float ls[4], lq[4];
    int wave = threadIdx.x >> 6;
    if ((threadIdx.x & 63) == 0) { ls[wave] = s; lq[wave] = q; }
    __syncthreads();
    if (threadIdx.x == 0) {
        atomicAdd(&stats[c],      ls[0] + ls[1] + ls[2] + ls[3]);
        atomicAdd(&stats[PL + c], lq[0] + lq[1] + lq[2] + lq[3]);
    }
}

__global__ __launch_bounds__(256) void k_norm(float* __restrict__ out,
                                              const float* __restrict__ stats,
                                              const float* __restrict__ gamma,
                                              const float* __restrict__ beta) {
    size_t idx = (size_t)blockIdx.x * 256 + threadIdx.x;
    int c = (int)((idx >> 14) & (PL - 1));
    float4 v = ((const float4*)out)[idx];
    float n = (float)NPIX;
    float mean = stats[c] / n;
    float var = stats[PL + c] / n - mean * mean;
    float sc = gamma[c] * rsqrtf(var + 1e-5f);
    float bs = beta[c] - mean * sc;
    v.x = fmaf(v.x, sc, bs);
    v.y = fmaf(v.y, sc, bs);
    v.z = fmaf(v.z, sc, bs);
    v.w = fmaf(v.w, sc, bs);
    ((float4*)out)[idx] = v;
}

extern "C" void kernel_launch(void* const* d_in, const int* in_sizes, int n_in,
                              void* d_out, int out_size, void* d_ws, size_t ws_size,
                              hipStream_t stream) {
    const float* x     = (const float*)d_in[0];
    const float* guide = (const float*)d_in[1];
    const float* Wc    = (const float*)d_in[2];
    const float* gamma = (const float*)d_in[3];
    const float* beta  = (const float*)d_in[4];
    float* out = (float*)d_out;

    char* ws = (char*)d_ws;
    unsigned short* xvb = (unsigned short*)(ws + XV_OFF);
    float* y1    = (float*)(ws + Y1_OFF);
    float* stats = (float*)(ws + STATS_OFF);

    hipMemsetAsync(stats, 0, 2 * PL * sizeof(float), stream);
    k_gemm_lo<<<512, 512, 0, stream>>>(x, Wc, y1);
    k_conv_hi<<<1024, 512, 0, stream>>>(guide, Wc, y1, xvb);
    k_attn<<<1024, 256, 0, stream>>>(guide, xvb, out);
    k_stats<<<BB * PL * 4, 256, 0, stream>>>(out, stats);
    k_norm<<<(NPIX * PL) / (256 * 4), 256, 0, stream>>>(out, stats, gamma, beta);
}

// Round 7
// 256.948 us; speedup vs baseline: 1.9601x; 1.2377x over previous
//
#include <hip/hip_runtime.h>
#include <math.h>

#define BB 4
#define CIN 256
#define GC 64
#define PL 64
#define HL 128
#define WL 128
#define HH 256
#define WW 256
#define HWLO (HL*WL)             /* 16384 */
#define HW (HH*WW)               /* 65536 */
#define NPIX (BB*HW)

typedef __attribute__((ext_vector_type(8))) short bf16x8;
typedef __attribute__((ext_vector_type(4))) float f32x4;

/* ws layout */
#define XV_OFF 0u                 /* bf16 xv: 33554432 B */
#define Y1_OFF 33554432u          /* fp32 y1: 16777216 B */
#define STATS_OFF 50331648u       /* 128 floats */
#define PB_OFF 50332672u          /* per-block partials: 1024*128 floats = 512 KB */

static __device__ __forceinline__ unsigned short f2bf(float f) {
    unsigned int u = __float_as_uint(f);
    u = (u + 0x7FFFu + ((u >> 16) & 1u)) >> 16;   /* RNE */
    return (unsigned short)u;
}
static __device__ __forceinline__ float bf2f(unsigned short s) {
    return __uint_as_float(((unsigned int)s) << 16);
}

/* y1[b][64][128*128] = W_x(64x256) * x  — bf16 MFMA GEMM, low-res. */
__global__ __launch_bounds__(512) void k_gemm_lo(const float* __restrict__ x,
                                                 const float* __restrict__ Wc,
                                                 float* __restrict__ y1) {
    __shared__ unsigned short lw[64 * 264];   /* W bf16 [64][256+8] */
    __shared__ unsigned short la[128 * 40];   /* act bf16 [128 px][32+8 k] */
    int t = threadIdx.x;
    int b = blockIdx.x >> 7;
    int row = blockIdx.x & 127;
    int lane = t & 63, wid = t >> 6;
    int g = lane >> 4, fr = lane & 15;

    for (int i = t; i < 64 * 256; i += 512) {
        int m = i >> 8, k = i & 255;
        lw[m * 264 + k] = f2bf(Wc[m * 320 + k]);
    }

    f32x4 acc[4];
#pragma unroll
    for (int m = 0; m < 4; ++m) acc[m] = (f32x4){0.f, 0.f, 0.f, 0.f};

    const float* xb = x + (size_t)b * CIN * HWLO + row * WL;
    int px = t & 127, kg = t >> 7;

    for (int kt = 0; kt < 8; ++kt) {
        int k0 = kt * 32;
        short pk[8];
#pragma unroll
        for (int j = 0; j < 8; ++j)
            pk[j] = (short)f2bf(xb[(size_t)(k0 + kg * 8 + j) * HWLO + px]);
        __syncthreads();
        *(bf16x8*)(&la[px * 40 + kg * 8]) = *(bf16x8*)pk;
        __syncthreads();
        bf16x8 bfr = *(const bf16x8*)(&la[(wid * 16 + fr) * 40 + g * 8]);
#pragma unroll
        for (int m = 0; m < 4; ++m) {
            bf16x8 af = *(const bf16x8*)(&lw[(m * 16 + fr) * 264 + k0 + g * 8]);
            acc[m] = __builtin_amdgcn_mfma_f32_16x16x32_bf16(af, bfr, acc[m], 0, 0, 0);
        }
    }

    float* yb = y1 + (size_t)b * 64 * HWLO + row * WL + wid * 16 + fr;
#pragma unroll
    for (int m = 0; m < 4; ++m)
#pragma unroll
        for (int r = 0; r < 4; ++r)
            yb[(size_t)(m * 16 + g * 4 + r) * HWLO] = acc[m][r];
}

/* xv[b][64][256*256] (bf16) = upsample(y1) + W_g(64x64) * guide. */
__global__ __launch_bounds__(512) void k_conv_hi(const float* __restrict__ guide,
                                                 const float* __restrict__ Wc,
                                                 const float* __restrict__ y1,
                                                 unsigned short* __restrict__ xv) {
    __shared__ unsigned short lg[256 * 72];
    __shared__ unsigned short lw[64 * 72];
    int t = threadIdx.x;
    int bid = blockIdx.x;
    int swz = (bid & 7) * 128 + (bid >> 3);
    int b = swz >> 8, h = swz & 255;
    int lane = t & 63, wid = t >> 6, g = lane >> 4, fr = lane & 15;

    for (int i = t; i < 64 * 64; i += 512) {
        int m = i >> 6, k = i & 63;
        lw[m * 72 + k] = f2bf(Wc[m * 320 + 256 + k]);
    }
    const float* gb = guide + (size_t)b * GC * HW + (size_t)h * WW;
#pragma unroll
    for (int q = 0; q < 4; ++q) {
        int a = t + q * 512;
        int px = a & 255, kg = a >> 8;
        short pk[8];
#pragma unroll
        for (int j = 0; j < 8; ++j)
            pk[j] = (short)f2bf(gb[(size_t)(kg * 8 + j) * HW + px]);
        *(bf16x8*)(&lg[px * 72 + kg * 8]) = *(bf16x8*)pk;
    }
    __syncthreads();

    f32x4 acc[4][2];
#pragma unroll
    for (int m = 0; m < 4; ++m)
#pragma unroll
        for (int n = 0; n < 2; ++n) acc[m][n] = (f32x4){0.f, 0.f, 0.f, 0.f};

#pragma unroll
    for (int kt = 0; kt < 2; ++kt) {
        bf16x8 bfr[2];
#pragma unroll
        for (int n = 0; n < 2; ++n)
            bfr[n] = *(const bf16x8*)(&lg[(wid * 32 + n * 16 + fr) * 72 + kt * 32 + g * 8]);
#pragma unroll
        for (int m = 0; m < 4; ++m) {
            bf16x8 af = *(const bf16x8*)(&lw[(m * 16 + fr) * 72 + kt * 32 + g * 8]);
#pragma unroll
            for (int n = 0; n < 2; ++n)
                acc[m][n] = __builtin_amdgcn_mfma_f32_16x16x32_bf16(af, bfr[n], acc[m][n], 0, 0, 0);
        }
    }
    __syncthreads();

    float* yb = (float*)lg;
    int m0 = h >> 1; int iy0, iy1; float wy0;
    if (h & 1) { iy0 = m0; iy1 = (m0 + 1 < HL) ? m0 + 1 : HL - 1; wy0 = 0.75f; }
    else       { iy0 = (m0 - 1 >= 0) ? m0 - 1 : 0; iy1 = m0;      wy0 = 0.25f; }
    float wy1 = 1.f - wy0;
    const float* y1b = y1 + (size_t)b * 64 * HWLO;
    for (int i = t; i < 64 * 128; i += 512) {
        int ch = i >> 7, ix = i & 127;
        yb[ch * 132 + ix] = wy0 * y1b[(size_t)ch * HWLO + iy0 * WL + ix]
                          + wy1 * y1b[(size_t)ch * HWLO + iy1 * WL + ix];
    }
    __syncthreads();

    int ix0v[2], ix1v[2]; float wx0v[2];
#pragma unroll
    for (int n = 0; n < 2; ++n) {
        int w = wid * 32 + n * 16 + fr;
        int mm = w >> 1;
        if (w & 1) { ix0v[n] = mm; ix1v[n] = (mm + 1 < WL) ? mm + 1 : WL - 1; wx0v[n] = 0.75f; }
        else       { ix0v[n] = (mm - 1 >= 0) ? mm - 1 : 0; ix1v[n] = mm;      wx0v[n] = 0.25f; }
    }
    unsigned short* xb = xv + (size_t)b * 64 * HW + (size_t)h * WW;
#pragma unroll
    for (int m = 0; m < 4; ++m)
#pragma unroll
        for (int n = 0; n < 2; ++n) {
            int w = wid * 32 + n * 16 + fr;
#pragma unroll
            for (int r = 0; r < 4; ++r) {
                int ch = m * 16 + g * 4 + r;
                float up = wx0v[n] * yb[ch * 132 + ix0v[n]]
                         + (1.f - wx0v[n]) * yb[ch * 132 + ix1v[n]];
                xb[(size_t)ch * HW + w] = f2bf(acc[m][n][r] + up);
            }
        }
}

/* local 3x3 attention with register-prefetch pipeline + fused BN partial stats.
 * Block = one row h (256 px, 1 px/thread). pb[bid][0..63]=sum, [64..127]=sumsq. */
__global__ __launch_bounds__(256) void k_attn(const float* __restrict__ guide,
                                              const unsigned short* __restrict__ xv,
                                              float* __restrict__ out,
                                              float* __restrict__ pb) {
    __shared__ float ls[8][3][264];
    __shared__ float lo[8][256];
    __shared__ float part[64][2];
    int t = threadIdx.x;
    int bid = blockIdx.x;
    int swz = (bid & 7) * 128 + (bid >> 3);
    int b = swz >> 8, h = swz & 255;
    bool rok[3] = { h > 0, true, h < HH - 1 };
    int hr[3] = { h > 0 ? h - 1 : 0, h, h < HH - 1 ? h + 1 : HH - 1 };

    /* persistent halo zeros ([0] and [257] never overwritten by stage writes) */
    if (t < 48) { int cc = t / 6, rem = t % 6; ls[cc][rem >> 1][(rem & 1) ? 257 : 0] = 0.f; }
    if (t < 128) part[t >> 1][t & 1] = 0.f;

    float s[9];
#pragma unroll
    for (int k = 0; k < 9; ++k) s[k] = 0.f;

    /* ---- score phase: prefetch-pipelined over 8 chunks of 8 channels ---- */
    const float* gB = guide + (size_t)b * GC * HW;
    float pf[24];
#pragma unroll
    for (int cc = 0; cc < 8; ++cc)
#pragma unroll
        for (int r = 0; r < 3; ++r)
            pf[cc * 3 + r] = rok[r] ? gB[(size_t)cc * HW + (size_t)hr[r] * WW + t] : 0.f;

    for (int c0 = 0; c0 < GC; c0 += 8) {
        __syncthreads();
#pragma unroll
        for (int cc = 0; cc < 8; ++cc)
#pragma unroll
            for (int r = 0; r < 3; ++r)
                ls[cc][r][1 + t] = pf[cc * 3 + r];
        __syncthreads();
        if (c0 + 8 < GC) {
#pragma unroll
            for (int cc = 0; cc < 8; ++cc)
#pragma unroll
                for (int r = 0; r < 3; ++r)
                    pf[cc * 3 + r] = rok[r] ? gB[(size_t)(c0 + 8 + cc) * HW + (size_t)hr[r] * WW + t] : 0.f;
        }
#pragma unroll
        for (int cc = 0; cc < 8; ++cc) {
            float q = ls[cc][1][1 + t];
#pragma unroll
            for (int r = 0; r < 3; ++r)
#pragma unroll
                for (int dj = 0; dj < 3; ++dj)
                    s[r * 3 + dj] = fmaf(q, ls[cc][r][t + dj], s[r * 3 + dj]);
        }
    }

    /* softmax over 9 (zero scores for OOB = reference zero-pad semantics) */
    float mx = s[0] * 0.125f;
#pragma unroll
    for (int k = 0; k < 9; ++k) { s[k] *= 0.125f; mx = fmaxf(mx, s[k]); }
    float den = 0.f;
#pragma unroll
    for (int k = 0; k < 9; ++k) { s[k] = __expf(s[k] - mx); den += s[k]; }
    float inv = 1.f / den;
#pragma unroll
    for (int k = 0; k < 9; ++k) s[k] *= inv;

    /* ---- PV phase: prefetch-pipelined, with per-chunk stats reduction ---- */
    const unsigned short* vB = xv + (size_t)b * 64 * HW;
    float* oB = out + (size_t)b * 64 * HW + (size_t)h * WW + t;
    int rcc = t >> 5, rln = t & 31;

    unsigned short pfu[24];
#pragma unroll
    for (int cc = 0; cc < 8; ++cc)
#pragma unroll
        for (int r = 0; r < 3; ++r)
            pfu[cc * 3 + r] = rok[r] ? vB[(size_t)cc * HW + (size_t)hr[r] * WW + t] : (unsigned short)0;

    for (int c0 = 0; c0 < PL; c0 += 8) {
        __syncthreads();
#pragma unroll
        for (int cc = 0; cc < 8; ++cc)
#pragma unroll
            for (int r = 0; r < 3; ++r)
                ls[cc][r][1 + t] = bf2f(pfu[cc * 3 + r]);
        if (c0 > 0) {            /* reduce previous chunk's lo -> part */
            float sv = 0.f, qv = 0.f;
#pragma unroll
            for (int j = 0; j < 8; ++j) {
                float v = lo[rcc][rln + 32 * j];
                sv += v; qv = fmaf(v, v, qv);
            }
#pragma unroll
            for (int d = 16; d >= 1; d >>= 1) { sv += __shfl_xor(sv, d); qv += __shfl_xor(qv, d); }
            if (rln == 0) { part[c0 - 8 + rcc][0] += sv; part[c0 - 8 + rcc][1] += qv; }
        }
        __syncthreads();
        if (c0 + 8 < PL) {
#pragma unroll
            for (int cc = 0; cc < 8; ++cc)
#pragma unroll
                for (int r = 0; r < 3; ++r)
                    pfu[cc * 3 + r] = rok[r] ? vB[(size_t)(c0 + 8 + cc) * HW + (size_t)hr[r] * WW + t] : (unsigned short)0;
        }
#pragma unroll
        for (int cc = 0; cc < 8; ++cc) {
            float o = 0.f;
#pragma unroll
            for (int r = 0; r < 3; ++r)
#pragma unroll
                for (int dj = 0; dj < 3; ++dj)
                    o = fmaf(s[r * 3 + dj], ls[cc][r][t + dj], o);
            oB[(size_t)(c0 + cc) * HW] = o;
            lo[cc][t] = o;
        }
    }
    __syncthreads();
    {   /* reduce final chunk */
        float sv = 0.f, qv = 0.f;
#pragma unroll
        for (int j = 0; j < 8; ++j) {
            float v = lo[rcc][rln + 32 * j];
            sv += v; qv = fmaf(v, v, qv);
        }
#pragma unroll
        for (int d = 16; d >= 1; d >>= 1) { sv += __shfl_xor(sv, d); qv += __shfl_xor(qv, d); }
        if (rln == 0) { part[56 + rcc][0] += sv; part[56 + rcc][1] += qv; }
    }
    __syncthreads();
    if (t < 128) pb[(size_t)bid * 128 + (t & 1) * 64 + (t >> 1)] = part[t >> 1][t & 1];
}

/* stats[c] = sum over 1024 block-partials; c in [0,128): 0-63 sum, 64-127 sumsq */
__global__ __launch_bounds__(256) void k_reduce(const float* __restrict__ pb,
                                                float* __restrict__ stats) {
    int c = blockIdx.x;
    float acc = 0.f;
#pragma unroll
    for (int i = 0; i < 4; ++i)
        acc += pb[(size_t)(threadIdx.x + i * 256) * 128 + c];
#pragma unroll
    for (int d = 32; d >= 1; d >>= 1) acc += __shfl_xor(acc, d);
    __shared__ float lred[4];
    if ((threadIdx.x & 63) == 0) lred[threadIdx.x >> 6] = acc;
    __syncthreads();
    if (threadIdx.x == 0) stats[c] = lred[0] + lred[1] + lred[2] + lred[3];
}

__global__ __launch_bounds__(256) void k_norm(float* __restrict__ out,
                                              const float* __restrict__ stats,
                                              const float* __restrict__ gamma,
                                              const float* __restrict__ beta) {
    size_t idx = (size_t)blockIdx.x * 256 + threadIdx.x;
    int c = (int)((idx >> 14) & (PL - 1));
    float4 v = ((const float4*)out)[idx];
    float n = (float)NPIX;
    float mean = stats[c] / n;
    float var = stats[PL + c] / n - mean * mean;
    float sc = gamma[c] * rsqrtf(var + 1e-5f);
    float bs = beta[c] - mean * sc;
    v.x = fmaf(v.x, sc, bs);
    v.y = fmaf(v.y, sc, bs);
    v.z = fmaf(v.z, sc, bs);
    v.w = fmaf(v.w, sc, bs);
    ((float4*)out)[idx] = v;
}

extern "C" void kernel_launch(void* const* d_in, const int* in_sizes, int n_in,
                              void* d_out, int out_size, void* d_ws, size_t ws_size,
                              hipStream_t stream) {
    const float* x     = (const float*)d_in[0];
    const float* guide = (const float*)d_in[1];
    const float* Wc    = (const float*)d_in[2];
    const float* gamma = (const float*)d_in[3];
    const float* beta  = (const float*)d_in[4];
    float* out = (float*)d_out;

    char* ws = (char*)d_ws;
    unsigned short* xvb = (unsigned short*)(ws + XV_OFF);
    float* y1    = (float*)(ws + Y1_OFF);
    float* stats = (float*)(ws + STATS_OFF);
    float* pb    = (float*)(ws + PB_OFF);

    k_gemm_lo<<<512, 512, 0, stream>>>(x, Wc, y1);
    k_conv_hi<<<1024, 512, 0, stream>>>(guide, Wc, y1, xvb);
    k_attn<<<1024, 256, 0, stream>>>(guide, xvb, out, pb);
    k_reduce<<<128, 256, 0, stream>>>(pb, stats);
    k_norm<<<(NPIX * PL) / (256 * 4), 256, 0, stream>>>(out, stats, gamma, beta);
}